// Round 16
// baseline (231.326 us; speedup 1.0000x reference)
//
#include <hip/hip_runtime.h>

// DoubleSin via f16 MFMA (16x16x32), zero-LDS, fused branches.
// Round-16 = round-15 with ILP x2 and __launch_bounds__(256,3):
// target 3 waves/SIMD. Budget 512/3 = 170 regs/wave; ILP x2 measured
// 100 VGPR + 64 AGPR ~= 164 <= 170 -> fits WITHOUT forced spills (unlike
// round-5's 128-cap on a 200-reg kernel). VALUBusy was 77.8% at 2 waves/SIMD
// -> the remaining idle issue slots are occupancy, not ILP (r14->r15 showed
// ILP x4 additions gained little). +50% TLP should saturate the VALU pipe.
// Keeps: revolutions v_sin fold (r15), f16 single-term (r12), fused branches
// + atomic accumulate (r8).
// Tripwire: FETCH ~8.4 MB must not balloon (spill signature -> revert).

typedef __fp16 h8v __attribute__((ext_vector_type(8)));
typedef __fp16 h2v __attribute__((ext_vector_type(2)));
typedef __attribute__((ext_vector_type(4))) float f4v;

union H8U { h8v v; h2v p[4]; };

#define R2PI  0.15915494309189535f
#define TWOPI 6.283185307179586f

__device__ __forceinline__ float sin_rev(float x) {   // sin(2*pi*x)
    float r;
    asm("v_sin_f32 %0, %1" : "=v"(r) : "v"(x));
    return r;
}

#define MFMA16(a, b, c) __builtin_amdgcn_mfma_f32_16x16x32_f16((a), (b), (c), 0, 0, 0)

// g~(q~) = q~ + sin_rev(q~)^2 * r2pi on all 16 accs, then f16 B fragments
__device__ __forceinline__ void act_frags(f4v (&acc)[4], h8v (&B)[2]) {
    #pragma unroll
    for (int t = 0; t < 4; ++t) {
        #pragma unroll
        for (int j = 0; j < 4; ++j) {
            float q = acc[t][j];
            float s = sin_rev(q);
            acc[t][j] = fmaf(s * s, R2PI, q);
        }
    }
    #pragma unroll
    for (int s2 = 0; s2 < 2; ++s2) {
        H8U u;
        u.p[0] = __builtin_amdgcn_cvt_pkrtz(acc[2 * s2][0],     acc[2 * s2][1]);
        u.p[1] = __builtin_amdgcn_cvt_pkrtz(acc[2 * s2][2],     acc[2 * s2][3]);
        u.p[2] = __builtin_amdgcn_cvt_pkrtz(acc[2 * s2 + 1][0], acc[2 * s2 + 1][1]);
        u.p[3] = __builtin_amdgcn_cvt_pkrtz(acc[2 * s2 + 1][2], acc[2 * s2 + 1][3]);
        B[s2] = u.v;
    }
}

__global__ __launch_bounds__(256, 3) void mlp_fused(
    const float* __restrict__ x,
    const float* __restrict__ W1a, const float* __restrict__ b1a, const float* __restrict__ a1a,
    const float* __restrict__ W2a, const float* __restrict__ b2a, const float* __restrict__ a2a,
    const float* __restrict__ W3a, const float* __restrict__ b3a, const float* __restrict__ a3a,
    const float* __restrict__ W4a, const float* __restrict__ b4a,
    const float* __restrict__ W1b, const float* __restrict__ b1b, const float* __restrict__ a1b,
    const float* __restrict__ W2b, const float* __restrict__ b2b, const float* __restrict__ a2b,
    const float* __restrict__ W3b, const float* __restrict__ b3b, const float* __restrict__ a3b,
    const float* __restrict__ W4b, const float* __restrict__ b4b,
    float* __restrict__ out, int n)
{
    const int lane = threadIdx.x & 63;
    const int col  = lane & 15;
    const int g    = lane >> 4;
    const int br   = (int)(blockIdx.x & 1);
    const int sub  = (int)(blockIdx.x >> 1);
    const int wid  = sub * 4 + (int)(threadIdx.x >> 6);
    const int nwaves = (int)((gridDim.x >> 1) << 2);     // waves per branch
    const int nst = n >> 5;                              // 32-point super-tiles
    const float xscale = br ? 2.0f : 1.0f;

    const float* W1 = br ? W1b : W1a;  const float* b1 = br ? b1b : b1a;  const float* a1 = br ? a1b : a1a;
    const float* W2 = br ? W2b : W2a;  const float* b2 = br ? b2b : b2a;  const float* a2 = br ? a2b : a2a;
    const float* W3 = br ? W3b : W3a;  const float* b3 = br ? b3b : b3a;  const float* a3 = br ? a3b : a3a;
    const float* W4 = br ? W4b : W4a;  const float* b4 = br ? b4b : b4a;

    // ---------------- preamble: fold params, build weight fragments --------
    // Layer 1 (VALU, revolutions): q~1 = (r2pi*xscale*a1*W1)*x + (r2pi*a1*b1)
    f4v w1p[4], b1p[4];
    #pragma unroll
    for (int t = 0; t < 4; ++t) {
        const int c0 = 16 * t + 4 * g;
        const f4v a1v = *(const f4v*)(a1 + c0);
        w1p[t] = (a1v * (xscale * R2PI)) * *(const f4v*)(W1 + c0);
        b1p[t] = (a1v * R2PI) * *(const f4v*)(b1 + c0);
    }

    // Layers 2,3 fragments (f16 RNE): W'[o][k] = aout[o] * W[o][k] / ain[k]
    // (unchanged by the revolutions fold: 2pi/r2pi cancel)
    h8v W2f[4][2], W3f[4][2];
    #pragma unroll
    for (int L = 0; L < 2; ++L) {
        const float* W    = L ? W3 : W2;
        const float* aout = L ? a3 : a2;
        const float* ain  = L ? a2 : a1;
        #pragma unroll
        for (int s = 0; s < 2; ++s) {
            const int kb = 32 * s + 4 * g;
            const f4v aia = *(const f4v*)(ain + kb);
            const f4v aib = *(const f4v*)(ain + kb + 16);
            float ra[8];
            #pragma unroll
            for (int j = 0; j < 4; ++j) { ra[j] = 1.0f / aia[j]; ra[4 + j] = 1.0f / aib[j]; }
            #pragma unroll
            for (int t = 0; t < 4; ++t) {
                const int o = 16 * t + col;
                const f4v wa = *(const f4v*)(W + o * 64 + kb);
                const f4v wb = *(const f4v*)(W + o * 64 + kb + 16);
                const float ao = aout[o];
                h8v hh;
                #pragma unroll
                for (int j = 0; j < 8; ++j) {
                    const float wv = (j < 4) ? wa[j & 3] : wb[j & 3];
                    hh[j] = (__fp16)(ao * wv * ra[j]);
                }
                if (L == 0) W2f[t][s] = hh;
                else        W3f[t][s] = hh;
            }
        }
    }

    // biases scaled to revolutions; w4'' = (W4/a3)*2pi
    f4v bias2[4], bias3[4], w4p[4];
    #pragma unroll
    for (int t = 0; t < 4; ++t) {
        const int c0 = 16 * t + 4 * g;
        bias2[t] = *(const f4v*)(b2 + c0) * *(const f4v*)(a2 + c0) * R2PI;
        bias3[t] = *(const f4v*)(b3 + c0) * *(const f4v*)(a3 + c0) * R2PI;
        w4p[t]   = *(const f4v*)(W4 + c0) / *(const f4v*)(a3 + c0) * TWOPI;
    }
    const float b4v = b4[0];

    // ---------------- main loop over 32-point super-tiles ------------------
    int st = wid;
    if (st >= nst) return;
    float xA = x[st * 32 + col];
    float xB = x[st * 32 + 16 + col];

    while (st < nst) {
        const int snext = st + nwaves;
        float xAn = 0.0f, xBn = 0.0f;
        if (snext < nst) {
            xAn = x[snext * 32 + col];
            xBn = x[snext * 32 + 16 + col];
        }

        // ---- layer 1 (fp32 VALU), both tiles ----
        f4v accA[4], accB[4];
        #pragma unroll
        for (int t = 0; t < 4; ++t) {
            #pragma unroll
            for (int j = 0; j < 4; ++j) {
                accA[t][j] = fmaf(w1p[t][j], xA, b1p[t][j]);
                accB[t][j] = fmaf(w1p[t][j], xB, b1p[t][j]);
            }
        }
        h8v BA[2], BB[2];
        act_frags(accA, BA);
        act_frags(accB, BB);

        // ---- layer 2, both tiles ----
        #pragma unroll
        for (int t = 0; t < 4; ++t) {
            f4v dA = bias2[t], dB = bias2[t];
            #pragma unroll
            for (int s = 0; s < 2; ++s) {
                dA = MFMA16(W2f[t][s], BA[s], dA);
                dB = MFMA16(W2f[t][s], BB[s], dB);
            }
            accA[t] = dA; accB[t] = dB;
        }
        act_frags(accA, BA);
        act_frags(accB, BB);

        // ---- layer 3, both tiles ----
        #pragma unroll
        for (int t = 0; t < 4; ++t) {
            f4v dA = bias3[t], dB = bias3[t];
            #pragma unroll
            for (int s = 0; s < 2; ++s) {
                dA = MFMA16(W3f[t][s], BA[s], dA);
                dB = MFMA16(W3f[t][s], BB[s], dB);
            }
            accA[t] = dA; accB[t] = dB;
        }
        #pragma unroll
        for (int t = 0; t < 4; ++t) {
            #pragma unroll
            for (int j = 0; j < 4; ++j) {
                float qA = accA[t][j], qB = accB[t][j];
                float sA = sin_rev(qA), sB = sin_rev(qB);
                accA[t][j] = fmaf(sA * sA, R2PI, qA);
                accB[t][j] = fmaf(sB * sB, R2PI, qB);
            }
        }

        // ---- layer 4, both tiles ----
        float pA = 0.0f, pB = 0.0f;
        #pragma unroll
        for (int t = 0; t < 4; ++t) {
            #pragma unroll
            for (int j = 0; j < 4; ++j) {
                pA = fmaf(w4p[t][j], accA[t][j], pA);
                pB = fmaf(w4p[t][j], accB[t][j], pB);
            }
        }
        pA += __shfl_xor(pA, 16); pA += __shfl_xor(pA, 32);
        pB += __shfl_xor(pB, 16); pB += __shfl_xor(pB, 32);

        const float pW = (lane < 16) ? pA : pB;
        if (lane < 32) unsafeAtomicAdd(&out[st * 32 + (lane & 31)], pW + b4v);

        st = snext; xA = xAn; xB = xBn;
    }
}

extern "C" void kernel_launch(void* const* d_in, const int* in_sizes, int n_in,
                              void* d_out, int out_size, void* d_ws, size_t ws_size,
                              hipStream_t stream) {
    const float* x   = (const float*)d_in[0];
    const float* W1a = (const float*)d_in[1];
    const float* b1a = (const float*)d_in[2];
    const float* a1a = (const float*)d_in[3];
    const float* W2a = (const float*)d_in[4];
    const float* b2a = (const float*)d_in[5];
    const float* a2a = (const float*)d_in[6];
    const float* W3a = (const float*)d_in[7];
    const float* b3a = (const float*)d_in[8];
    const float* a3a = (const float*)d_in[9];
    const float* W4a = (const float*)d_in[10];
    const float* b4a = (const float*)d_in[11];
    const float* W1b = (const float*)d_in[12];
    const float* b1b = (const float*)d_in[13];
    const float* a1b = (const float*)d_in[14];
    const float* W2b = (const float*)d_in[15];
    const float* b2b = (const float*)d_in[16];
    const float* a2b = (const float*)d_in[17];
    const float* W3b = (const float*)d_in[18];
    const float* b3b = (const float*)d_in[19];
    const float* a3b = (const float*)d_in[20];
    const float* W4b = (const float*)d_in[21];
    const float* b4b = (const float*)d_in[22];

    const int n = in_sizes[0];
    float* out = (float*)d_out;

    (void)hipMemsetAsync(out, 0, (size_t)n * sizeof(float), stream);
    mlp_fused<<<1024, 256, 0, stream>>>(x,
                                        W1a, b1a, a1a, W2a, b2a, a2a,
                                        W3a, b3a, a3a, W4a, b4a,
                                        W1b, b1b, a1b, W2b, b2b, a2b,
                                        W3b, b3b, a3b, W4b, b4b,
                                        out, n);
}

// Round 17
// 150.358 us; speedup vs baseline: 1.5385x; 1.5385x over previous
//
#include <hip/hip_runtime.h>

// DoubleSin via f16 MFMA (16x16x32), zero-LDS, fused branches.
// Round-17 = round-15 (best, 152 us) with ONE change: grid 1024 -> 512.
// Mechanism: 2 waves/SIMD cap -> 2048 residency slots. 1024 blocks = 4096
// waves = TWO sequential cohorts, each paying the weight-fragment preamble
// (128 uncoalesced loads/lane + folds) and ramp/tail. 512 blocks = exact
// fill, preamble once, and 32768 supertiles / 1024 waves-per-branch = exactly
// 32 iterations/wave, no remainder.
// Round-16 lesson: the 3-wave/SIMD tier clamps arch-VGPRs to 84 (not ~104;
// granularity + 64 AGPRs) -> spills. 2 waves/SIMD is the confirmed cap.
// Keeps: ILP x4 (r14), revolutions v_sin (r15), f16 single-term (r12),
// fused branches + atomic accumulate (r8).

typedef __fp16 h8v __attribute__((ext_vector_type(8)));
typedef __fp16 h2v __attribute__((ext_vector_type(2)));
typedef __attribute__((ext_vector_type(4))) float f4v;

union H8U { h8v v; h2v p[4]; };

#define R2PI  0.15915494309189535f
#define TWOPI 6.283185307179586f

__device__ __forceinline__ float sin_rev(float x) {   // sin(2*pi*x)
    float r;
    asm("v_sin_f32 %0, %1" : "=v"(r) : "v"(x));
    return r;
}

#define MFMA16(a, b, c) __builtin_amdgcn_mfma_f32_16x16x32_f16((a), (b), (c), 0, 0, 0)

// g~(q~) = q~ + sin_rev(q~)^2 * r2pi on all 16 accs, then f16 B fragments
__device__ __forceinline__ void act_frags(f4v (&acc)[4], h8v (&B)[2]) {
    #pragma unroll
    for (int t = 0; t < 4; ++t) {
        #pragma unroll
        for (int j = 0; j < 4; ++j) {
            float q = acc[t][j];
            float s = sin_rev(q);
            acc[t][j] = fmaf(s * s, R2PI, q);
        }
    }
    #pragma unroll
    for (int s2 = 0; s2 < 2; ++s2) {
        H8U u;
        u.p[0] = __builtin_amdgcn_cvt_pkrtz(acc[2 * s2][0],     acc[2 * s2][1]);
        u.p[1] = __builtin_amdgcn_cvt_pkrtz(acc[2 * s2][2],     acc[2 * s2][3]);
        u.p[2] = __builtin_amdgcn_cvt_pkrtz(acc[2 * s2 + 1][0], acc[2 * s2 + 1][1]);
        u.p[3] = __builtin_amdgcn_cvt_pkrtz(acc[2 * s2 + 1][2], acc[2 * s2 + 1][3]);
        B[s2] = u.v;
    }
}

__global__ __launch_bounds__(256, 2) void mlp_fused(
    const float* __restrict__ x,
    const float* __restrict__ W1a, const float* __restrict__ b1a, const float* __restrict__ a1a,
    const float* __restrict__ W2a, const float* __restrict__ b2a, const float* __restrict__ a2a,
    const float* __restrict__ W3a, const float* __restrict__ b3a, const float* __restrict__ a3a,
    const float* __restrict__ W4a, const float* __restrict__ b4a,
    const float* __restrict__ W1b, const float* __restrict__ b1b, const float* __restrict__ a1b,
    const float* __restrict__ W2b, const float* __restrict__ b2b, const float* __restrict__ a2b,
    const float* __restrict__ W3b, const float* __restrict__ b3b, const float* __restrict__ a3b,
    const float* __restrict__ W4b, const float* __restrict__ b4b,
    float* __restrict__ out, int n)
{
    const int lane = threadIdx.x & 63;
    const int col  = lane & 15;
    const int g    = lane >> 4;
    const int br   = (int)(blockIdx.x & 1);
    const int sub  = (int)(blockIdx.x >> 1);
    const int wid  = sub * 4 + (int)(threadIdx.x >> 6);
    const int nwaves = (int)((gridDim.x >> 1) << 2);     // waves per branch
    const int nst = n >> 6;                              // 64-point super-tiles
    const float xscale = br ? 2.0f : 1.0f;

    const float* W1 = br ? W1b : W1a;  const float* b1 = br ? b1b : b1a;  const float* a1 = br ? a1b : a1a;
    const float* W2 = br ? W2b : W2a;  const float* b2 = br ? b2b : b2a;  const float* a2 = br ? a2b : a2a;
    const float* W3 = br ? W3b : W3a;  const float* b3 = br ? b3b : b3a;  const float* a3 = br ? a3b : a3a;
    const float* W4 = br ? W4b : W4a;  const float* b4 = br ? b4b : b4a;

    // ---------------- preamble: fold params, build weight fragments --------
    // Layer 1 (VALU, revolutions): q~1 = (r2pi*xscale*a1*W1)*x + (r2pi*a1*b1)
    f4v w1p[4], b1p[4];
    #pragma unroll
    for (int t = 0; t < 4; ++t) {
        const int c0 = 16 * t + 4 * g;
        const f4v a1v = *(const f4v*)(a1 + c0);
        w1p[t] = (a1v * (xscale * R2PI)) * *(const f4v*)(W1 + c0);
        b1p[t] = (a1v * R2PI) * *(const f4v*)(b1 + c0);
    }

    // Layers 2,3 fragments (f16 RNE): W'[o][k] = aout[o] * W[o][k] / ain[k]
    // (unchanged by the revolutions fold: 2pi/r2pi cancel)
    h8v W2f[4][2], W3f[4][2];
    #pragma unroll
    for (int L = 0; L < 2; ++L) {
        const float* W    = L ? W3 : W2;
        const float* aout = L ? a3 : a2;
        const float* ain  = L ? a2 : a1;
        #pragma unroll
        for (int s = 0; s < 2; ++s) {
            const int kb = 32 * s + 4 * g;
            const f4v aia = *(const f4v*)(ain + kb);
            const f4v aib = *(const f4v*)(ain + kb + 16);
            float ra[8];
            #pragma unroll
            for (int j = 0; j < 4; ++j) { ra[j] = 1.0f / aia[j]; ra[4 + j] = 1.0f / aib[j]; }
            #pragma unroll
            for (int t = 0; t < 4; ++t) {
                const int o = 16 * t + col;
                const f4v wa = *(const f4v*)(W + o * 64 + kb);
                const f4v wb = *(const f4v*)(W + o * 64 + kb + 16);
                const float ao = aout[o];
                h8v hh;
                #pragma unroll
                for (int j = 0; j < 8; ++j) {
                    const float wv = (j < 4) ? wa[j & 3] : wb[j & 3];
                    hh[j] = (__fp16)(ao * wv * ra[j]);
                }
                if (L == 0) W2f[t][s] = hh;
                else        W3f[t][s] = hh;
            }
        }
    }

    // biases scaled to revolutions; w4'' = (W4/a3)*2pi
    f4v bias2[4], bias3[4], w4p[4];
    #pragma unroll
    for (int t = 0; t < 4; ++t) {
        const int c0 = 16 * t + 4 * g;
        bias2[t] = *(const f4v*)(b2 + c0) * *(const f4v*)(a2 + c0) * R2PI;
        bias3[t] = *(const f4v*)(b3 + c0) * *(const f4v*)(a3 + c0) * R2PI;
        w4p[t]   = *(const f4v*)(W4 + c0) / *(const f4v*)(a3 + c0) * TWOPI;
    }
    const float b4v = b4[0];

    // ---------------- main loop over 64-point super-tiles ------------------
    int st = wid;
    if (st >= nst) return;
    float xA = x[st * 64 + col];
    float xB = x[st * 64 + 16 + col];
    float xC = x[st * 64 + 32 + col];
    float xD = x[st * 64 + 48 + col];

    while (st < nst) {
        const int snext = st + nwaves;
        float xAn = 0.0f, xBn = 0.0f, xCn = 0.0f, xDn = 0.0f;
        if (snext < nst) {
            xAn = x[snext * 64 + col];
            xBn = x[snext * 64 + 16 + col];
            xCn = x[snext * 64 + 32 + col];
            xDn = x[snext * 64 + 48 + col];
        }

        // ---- layer 1 (fp32 VALU), 4 tiles ----
        f4v accA[4], accB[4], accC[4], accD[4];
        #pragma unroll
        for (int t = 0; t < 4; ++t) {
            #pragma unroll
            for (int j = 0; j < 4; ++j) {
                accA[t][j] = fmaf(w1p[t][j], xA, b1p[t][j]);
                accB[t][j] = fmaf(w1p[t][j], xB, b1p[t][j]);
                accC[t][j] = fmaf(w1p[t][j], xC, b1p[t][j]);
                accD[t][j] = fmaf(w1p[t][j], xD, b1p[t][j]);
            }
        }
        h8v BA[2], BB[2], BC[2], BD[2];
        act_frags(accA, BA);
        act_frags(accB, BB);
        act_frags(accC, BC);
        act_frags(accD, BD);

        // ---- layer 2, 4 tiles ----
        #pragma unroll
        for (int t = 0; t < 4; ++t) {
            f4v dA = bias2[t], dB = bias2[t], dC = bias2[t], dD = bias2[t];
            #pragma unroll
            for (int s = 0; s < 2; ++s) {
                dA = MFMA16(W2f[t][s], BA[s], dA);
                dB = MFMA16(W2f[t][s], BB[s], dB);
                dC = MFMA16(W2f[t][s], BC[s], dC);
                dD = MFMA16(W2f[t][s], BD[s], dD);
            }
            accA[t] = dA; accB[t] = dB; accC[t] = dC; accD[t] = dD;
        }
        act_frags(accA, BA);
        act_frags(accB, BB);
        act_frags(accC, BC);
        act_frags(accD, BD);

        // ---- layer 3, 4 tiles ----
        #pragma unroll
        for (int t = 0; t < 4; ++t) {
            f4v dA = bias3[t], dB = bias3[t], dC = bias3[t], dD = bias3[t];
            #pragma unroll
            for (int s = 0; s < 2; ++s) {
                dA = MFMA16(W3f[t][s], BA[s], dA);
                dB = MFMA16(W3f[t][s], BB[s], dB);
                dC = MFMA16(W3f[t][s], BC[s], dC);
                dD = MFMA16(W3f[t][s], BD[s], dD);
            }
            accA[t] = dA; accB[t] = dB; accC[t] = dC; accD[t] = dD;
        }
        #pragma unroll
        for (int t = 0; t < 4; ++t) {
            #pragma unroll
            for (int j = 0; j < 4; ++j) {
                float qA = accA[t][j], qB = accB[t][j];
                float qC = accC[t][j], qD = accD[t][j];
                float sA = sin_rev(qA), sB = sin_rev(qB);
                float sC = sin_rev(qC), sD = sin_rev(qD);
                accA[t][j] = fmaf(sA * sA, R2PI, qA);
                accB[t][j] = fmaf(sB * sB, R2PI, qB);
                accC[t][j] = fmaf(sC * sC, R2PI, qC);
                accD[t][j] = fmaf(sD * sD, R2PI, qD);
            }
        }

        // ---- layer 4, 4 tiles ----
        float pA = 0.0f, pB = 0.0f, pC = 0.0f, pD = 0.0f;
        #pragma unroll
        for (int t = 0; t < 4; ++t) {
            #pragma unroll
            for (int j = 0; j < 4; ++j) {
                pA = fmaf(w4p[t][j], accA[t][j], pA);
                pB = fmaf(w4p[t][j], accB[t][j], pB);
                pC = fmaf(w4p[t][j], accC[t][j], pC);
                pD = fmaf(w4p[t][j], accD[t][j], pD);
            }
        }
        pA += __shfl_xor(pA, 16); pA += __shfl_xor(pA, 32);
        pB += __shfl_xor(pB, 16); pB += __shfl_xor(pB, 32);
        pC += __shfl_xor(pC, 16); pC += __shfl_xor(pC, 32);
        pD += __shfl_xor(pD, 16); pD += __shfl_xor(pD, 32);

        float pW = pA;
        if (g == 1) pW = pB;
        if (g == 2) pW = pC;
        if (g == 3) pW = pD;
        unsafeAtomicAdd(&out[st * 64 + lane], pW + b4v);

        st = snext; xA = xAn; xB = xBn; xC = xCn; xD = xDn;
    }
}

extern "C" void kernel_launch(void* const* d_in, const int* in_sizes, int n_in,
                              void* d_out, int out_size, void* d_ws, size_t ws_size,
                              hipStream_t stream) {
    const float* x   = (const float*)d_in[0];
    const float* W1a = (const float*)d_in[1];
    const float* b1a = (const float*)d_in[2];
    const float* a1a = (const float*)d_in[3];
    const float* W2a = (const float*)d_in[4];
    const float* b2a = (const float*)d_in[5];
    const float* a2a = (const float*)d_in[6];
    const float* W3a = (const float*)d_in[7];
    const float* b3a = (const float*)d_in[8];
    const float* a3a = (const float*)d_in[9];
    const float* W4a = (const float*)d_in[10];
    const float* b4a = (const float*)d_in[11];
    const float* W1b = (const float*)d_in[12];
    const float* b1b = (const float*)d_in[13];
    const float* a1b = (const float*)d_in[14];
    const float* W2b = (const float*)d_in[15];
    const float* b2b = (const float*)d_in[16];
    const float* a2b = (const float*)d_in[17];
    const float* W3b = (const float*)d_in[18];
    const float* b3b = (const float*)d_in[19];
    const float* a3b = (const float*)d_in[20];
    const float* W4b = (const float*)d_in[21];
    const float* b4b = (const float*)d_in[22];

    const int n = in_sizes[0];
    float* out = (float*)d_out;

    (void)hipMemsetAsync(out, 0, (size_t)n * sizeof(float), stream);
    mlp_fused<<<512, 256, 0, stream>>>(x,
                                       W1a, b1a, a1a, W2a, b2a, a2a,
                                       W3a, b3a, a3a, W4a, b4a,
                                       W1b, b1b, a1b, W2b, b2b, a2b,
                                       W3b, b3b, a3b, W4b, b4b,
                                       out, n);
}